// Round 1
// baseline (103.415 us; speedup 1.0000x reference)
//
#include <hip/hip_runtime.h>
#include <math.h>

#define B_DIM   4
#define C_DIM   256
#define H_DIM   64
#define W_DIM   64
#define HW_DIM  4096   // H*W
#define NREF    4

// ---------------------------------------------------------------------------
// Stage 1: Q/K/V projections.
//   Out_m[b][hw][o] = sum_c W_m[o][c] * x[b][c][hw] + b_m[o]
// stored TRANSPOSED as (B, HW, C) so stage-2 gathers are coalesced rows.
// Block: 256 threads, tile 128 hw x 128 o, 8x8 per thread, f32 FMA.
// ---------------------------------------------------------------------------
__global__ __launch_bounds__(256) void proj_kernel(
    const float* __restrict__ x,
    const float* __restrict__ Wq, const float* __restrict__ bq,
    const float* __restrict__ Wk, const float* __restrict__ bk,
    const float* __restrict__ Wv, const float* __restrict__ bv,
    float* __restrict__ Qt, float* __restrict__ Kt, float* __restrict__ Vt)
{
    const int m  = blockIdx.z % 3;       // 0=Q 1=K 2=V
    const int b  = blockIdx.z / 3;
    const float* Wm = (m == 0) ? Wq : (m == 1) ? Wk : Wv;
    const float* bm = (m == 0) ? bq : (m == 1) ? bk : bv;
    float* Out      = (m == 0) ? Qt : (m == 1) ? Kt : Vt;

    const int hw0 = blockIdx.x * 128;
    const int o0  = blockIdx.y * 128;

    __shared__ float x_s[16][128];   // [c][hw]
    __shared__ float w_s[16][128];   // [c][o]  (transposed at store)

    const int t  = threadIdx.x;
    const int tx = t & 15;   // hw group: hw_local = tx*8 + i
    const int ty = t >> 4;   // o  group: o_local  = ty*8 + j

    float acc[8][8];
#pragma unroll
    for (int i = 0; i < 8; ++i)
#pragma unroll
        for (int j = 0; j < 8; ++j) acc[i][j] = 0.0f;

    const float* xb = x + (size_t)b * C_DIM * HW_DIM;

    for (int c0 = 0; c0 < C_DIM; c0 += 16) {
        // ---- load x chunk: 16 c-rows x 128 hw, coalesced 512B rows ----
        {
            const int cr  = t >> 4;          // 0..15
            const int col = (t & 15) * 8;    // 0..120
            const float* src = xb + (size_t)(c0 + cr) * HW_DIM + hw0 + col;
            float4 v0 = *(const float4*)(src);
            float4 v1 = *(const float4*)(src + 4);
            *(float4*)&x_s[cr][col]     = v0;
            *(float4*)&x_s[cr][col + 4] = v1;
        }
        // ---- load W chunk (128 o-rows x 16 c) and transpose into LDS ----
        {
            const int r  = t >> 1;           // 0..127 (o row)
            const int cc = (t & 1) * 8;      // 0 or 8
            const float* src = Wm + (size_t)(o0 + r) * C_DIM + c0 + cc;
            float4 v0 = *(const float4*)(src);
            float4 v1 = *(const float4*)(src + 4);
            w_s[cc + 0][r] = v0.x; w_s[cc + 1][r] = v0.y;
            w_s[cc + 2][r] = v0.z; w_s[cc + 3][r] = v0.w;
            w_s[cc + 4][r] = v1.x; w_s[cc + 5][r] = v1.y;
            w_s[cc + 6][r] = v1.z; w_s[cc + 7][r] = v1.w;
        }
        __syncthreads();

#pragma unroll
        for (int c = 0; c < 16; ++c) {
            float a[8], w[8];
            *(float4*)&a[0] = *(const float4*)&x_s[c][tx * 8];
            *(float4*)&a[4] = *(const float4*)&x_s[c][tx * 8 + 4];
            *(float4*)&w[0] = *(const float4*)&w_s[c][ty * 8];
            *(float4*)&w[4] = *(const float4*)&w_s[c][ty * 8 + 4];
#pragma unroll
            for (int i = 0; i < 8; ++i)
#pragma unroll
                for (int j = 0; j < 8; ++j)
                    acc[i][j] = fmaf(a[i], w[j], acc[i][j]);
        }
        __syncthreads();
    }

    // ---- bias + store: Out[b][hw][o], 32B chunks per row; full row covered
    // by this block so L2 merges into complete lines before HBM.
    float bias[8];
#pragma unroll
    for (int j = 0; j < 8; ++j) bias[j] = bm[o0 + ty * 8 + j];

    float* outb = Out + ((size_t)b * HW_DIM + hw0) * C_DIM + o0;
#pragma unroll
    for (int i = 0; i < 8; ++i) {
        const int hw_l = tx * 8 + i;
        float* dst = outb + (size_t)hw_l * C_DIM + ty * 8;
        float4 v0, v1;
        v0.x = acc[i][0] + bias[0]; v0.y = acc[i][1] + bias[1];
        v0.z = acc[i][2] + bias[2]; v0.w = acc[i][3] + bias[3];
        v1.x = acc[i][4] + bias[4]; v1.y = acc[i][5] + bias[5];
        v1.z = acc[i][6] + bias[6]; v1.w = acc[i][7] + bias[7];
        *(float4*)(dst)     = v0;
        *(float4*)(dst + 4) = v1;
    }
}

// ---------------------------------------------------------------------------
// Stage 2: fused offsets -> indices -> gather K -> softmax -> gather V -> out.
// One wave (64 lanes) per pixel; lane owns 4 channels (float4).
// Block = 1024 threads = 16 waves = 16 consecutive pixels of one batch.
// Output transposed through LDS for coalesced (B,C,HW) stores.
// ---------------------------------------------------------------------------
__global__ __launch_bounds__(1024) void attn_kernel(
    const float* __restrict__ Qt,   // (B, HW, C)
    const float* __restrict__ Kt,
    const float* __restrict__ Vt,
    const float* __restrict__ Woff, // (8, C)
    const float* __restrict__ boff, // (8,)
    float* __restrict__ out)        // (B, C, HW)
{
    __shared__ float trans[16][260]; // [pixel][channel], padded

    const int t    = threadIdx.x;
    const int wave = t >> 6;       // 0..15 : pixel within block
    const int lane = t & 63;

    const int pix0 = blockIdx.x * 16;          // global pixel base
    const int b    = pix0 / HW_DIM;            // 16 | HW_DIM so no straddle
    const int hw   = (pix0 % HW_DIM) + wave;
    const int h    = hw >> 6;
    const int w    = hw & 63;

    // ---- load this pixel's Q row slice (4 channels per lane) ----
    const float* qrow = Qt + ((size_t)b * HW_DIM + hw) * C_DIM;
    float q[4];
    *(float4*)q = *(const float4*)(qrow + lane * 4);

    // ---- offset projection: 8 dot products over C, butterfly reduce ----
    float part[8];
#pragma unroll
    for (int j = 0; j < 8; ++j) {
        float4 wv = *(const float4*)(Woff + j * C_DIM + lane * 4);
        part[j] = fmaf(q[3], wv.w, fmaf(q[2], wv.z, fmaf(q[1], wv.y, q[0] * wv.x)));
    }
#pragma unroll
    for (int off = 1; off < 64; off <<= 1) {
#pragma unroll
        for (int j = 0; j < 8; ++j) part[j] += __shfl_xor(part[j], off);
    }

    // ---- indices: round-half-even + clip (matches jnp.round/clip) ----
    int idx[NREF];
#pragma unroll
    for (int n = 0; n < NREF; ++n) {
        const float ox = part[2 * n]     + boff[2 * n];
        const float oy = part[2 * n + 1] + boff[2 * n + 1];
        int rx = (int)rintf((float)w + ox);
        int ry = (int)rintf((float)h + oy);
        rx = min(max(rx, 0), W_DIM - 1);
        ry = min(max(ry, 0), H_DIM - 1);
        idx[n] = ry * W_DIM + rx;
    }

    // ---- logits: q . K[idx_n], butterfly reduce ----
    float logit[NREF];
#pragma unroll
    for (int n = 0; n < NREF; ++n) {
        const float* krow = Kt + ((size_t)b * HW_DIM + idx[n]) * C_DIM;
        float4 kv = *(const float4*)(krow + lane * 4);
        float lp = fmaf(q[3], kv.w, fmaf(q[2], kv.z, fmaf(q[1], kv.y, q[0] * kv.x)));
#pragma unroll
        for (int off = 1; off < 64; off <<= 1) lp += __shfl_xor(lp, off);
        logit[n] = lp;
    }

    // ---- softmax over n (all lanes replicate) ----
    float mx = fmaxf(fmaxf(logit[0], logit[1]), fmaxf(logit[2], logit[3]));
    float e[NREF], s = 0.0f;
#pragma unroll
    for (int n = 0; n < NREF; ++n) { e[n] = expf(logit[n] - mx); s += e[n]; }
    float wgt[NREF];
#pragma unroll
    for (int n = 0; n < NREF; ++n) wgt[n] = e[n] / s;

    // ---- output: sum_n wgt[n] * V[idx_n], 4 channels per lane ----
    float o4[4] = {0.f, 0.f, 0.f, 0.f};
#pragma unroll
    for (int n = 0; n < NREF; ++n) {
        const float* vrow = Vt + ((size_t)b * HW_DIM + idx[n]) * C_DIM;
        float4 vv = *(const float4*)(vrow + lane * 4);
        o4[0] = fmaf(wgt[n], vv.x, o4[0]);
        o4[1] = fmaf(wgt[n], vv.y, o4[1]);
        o4[2] = fmaf(wgt[n], vv.z, o4[2]);
        o4[3] = fmaf(wgt[n], vv.w, o4[3]);
    }

    // ---- transpose through LDS, store coalesced 64B runs ----
    *(float4*)&trans[wave][lane * 4] = *(float4*)o4;
    __syncthreads();

    float* ob = out + (size_t)b * C_DIM * HW_DIM + (pix0 % HW_DIM);
    const int px = t & 15;
#pragma unroll
    for (int cc = 0; cc < C_DIM; cc += 64) {
        const int c = cc + (t >> 4);
        ob[(size_t)c * HW_DIM + px] = trans[px][c];
    }
}

// ---------------------------------------------------------------------------
extern "C" void kernel_launch(void* const* d_in, const int* in_sizes, int n_in,
                              void* d_out, int out_size, void* d_ws, size_t ws_size,
                              hipStream_t stream) {
    const float* x    = (const float*)d_in[0];
    const float* Wq   = (const float*)d_in[1];
    const float* bq   = (const float*)d_in[2];
    const float* Wk   = (const float*)d_in[3];
    const float* bk   = (const float*)d_in[4];
    const float* Wv   = (const float*)d_in[5];
    const float* bv   = (const float*)d_in[6];
    const float* Woff = (const float*)d_in[7];
    const float* boff = (const float*)d_in[8];
    float* out = (float*)d_out;

    const size_t mat_elems = (size_t)B_DIM * HW_DIM * C_DIM; // 4,194,304
    float* Qt = (float*)d_ws;
    float* Kt = Qt + mat_elems;
    float* Vt = Kt + mat_elems;

    // Stage 1: 32 hw-tiles x 2 o-tiles x (3 matrices * 4 batches)
    dim3 g1(HW_DIM / 128, C_DIM / 128, 3 * B_DIM);
    proj_kernel<<<g1, dim3(256), 0, stream>>>(x, Wq, bq, Wk, bk, Wv, bv, Qt, Kt, Vt);

    // Stage 2: one block per 16 pixels
    dim3 g2((B_DIM * HW_DIM) / 16);
    attn_kernel<<<g2, dim3(1024), 0, stream>>>(Qt, Kt, Vt, Woff, boff, out);
}

// Round 2
// 82.945 us; speedup vs baseline: 1.2468x; 1.2468x over previous
//
#include <hip/hip_runtime.h>
#include <math.h>

#define B_DIM   4
#define C_DIM   256
#define H_DIM   64
#define W_DIM   64
#define HW_DIM  4096   // H*W
#define NREF    4

typedef unsigned short u16;
typedef __attribute__((ext_vector_type(4))) unsigned short u16x4;
typedef __attribute__((ext_vector_type(8))) short bf16x8;
typedef __attribute__((ext_vector_type(4))) float f32x4;

__device__ __forceinline__ u16 bf16_rne(float f) {
    unsigned u = __float_as_uint(f);
    u = u + 0x7FFFu + ((u >> 16) & 1u);
    return (u16)(u >> 16);
}
__device__ __forceinline__ float bf16_tof(u16 h) {
    return __uint_as_float(((unsigned)h) << 16);
}
__device__ __forceinline__ void gload16(const void* g, void* l) {
    __builtin_amdgcn_global_load_lds(
        (const __attribute__((address_space(1))) void*)g,
        (__attribute__((address_space(3))) void*)l, 16, 0, 0);
}

// ---------------------------------------------------------------------------
// x prep: (B, C, HW) f32  ->  (B*HW, C) bf16 hi + lo planes (transpose+split).
// ---------------------------------------------------------------------------
__global__ __launch_bounds__(256) void xsplit_kernel(
    const float* __restrict__ x, u16* __restrict__ xh, u16* __restrict__ xl)
{
    __shared__ float tile[64][65];
    const int b   = blockIdx.z;
    const int c0  = blockIdx.y * 64;
    const int hw0 = blockIdx.x * 64;
    const int t   = threadIdx.x;
    const int r4  = t >> 6;     // 0..3
    const int col = t & 63;

#pragma unroll
    for (int i = 0; i < 16; ++i) {
        const int row = i * 4 + r4;  // c index
        tile[row][col] = x[((size_t)b * C_DIM + c0 + row) * HW_DIM + hw0 + col];
    }
    __syncthreads();
#pragma unroll
    for (int i = 0; i < 16; ++i) {
        const int hwr = i * 4 + r4;        // hw row
        const float v = tile[col][hwr];    // [c][hw] transposed read
        const u16 h = bf16_rne(v);
        const float lo = v - bf16_tof(h);
        const size_t o = ((size_t)b * HW_DIM + hw0 + hwr) * C_DIM + c0 + col;
        xh[o] = h;
        xl[o] = bf16_rne(lo);
    }
}

// ---------------------------------------------------------------------------
// K/V projections via 3-pass split-bf16 MFMA.
//   Out[m][n] = sum_k A[m][k] * W[n][k] + b[n],  m = b*HW+hw, n = o, k = c
// Tile 128x128, BK=64, 4 waves (2x2), each wave 64x64 (4x4 frags of 16x16x32).
// A staged hi/lo via global_load_lds with pre-swizzled source (XOR st-swizzle);
// B (W, tiny) split f32->bf16 hi/lo in-kernel with swizzled ds_write.
// ---------------------------------------------------------------------------
__global__ __launch_bounds__(256) void kv_mfma(
    const u16* __restrict__ xh, const u16* __restrict__ xl,
    const float* __restrict__ Wk, const float* __restrict__ bk,
    const float* __restrict__ Wv, const float* __restrict__ bv,
    float* __restrict__ Kt, float* __restrict__ Vt)
{
    const int mat = blockIdx.z;
    const float* Wm  = mat ? Wv : Wk;
    const float* bm  = mat ? bv : bk;
    float*       Out = mat ? Vt : Kt;

    const int m0 = blockIdx.x * 128;
    const int n0 = blockIdx.y * 128;

    __shared__ u16 lds[32768];      // 64 KB: Ah, Al, Bh, Bl each [128][64]
    u16* Ah = lds;
    u16* Al = lds + 8192;
    u16* Bh = lds + 16384;
    u16* Bl = lds + 24576;

    const int t    = threadIdx.x;
    const int lane = t & 63;
    const int wv   = t >> 6;
    const int wm   = (wv >> 1) * 64;   // wave row (m) offset
    const int wn   = (wv & 1) * 64;    // wave col (n) offset

    f32x4 acc[4][4] = {};

    for (int kt = 0; kt < 4; ++kt) {
        const int k0 = kt * 64;

        // ---- stage A hi/lo: linear LDS dest, inverse-swizzled global src ----
#pragma unroll
        for (int it = 0; it < 4; ++it) {
            const int s   = it * 256 + t;       // 16B slot
            const int row = s >> 3;             // m-local
            const int sch = (s & 7) ^ (row & 7);
            const size_t goff = (size_t)(m0 + row) * C_DIM + k0 + sch * 8;
            gload16(xh + goff, (char*)Ah + s * 16);
            gload16(xl + goff, (char*)Al + s * 16);
        }
        // ---- stage B: read W f32, split, swizzled ds_write ----
#pragma unroll
        for (int i = 0; i < 8; ++i) {
            const int f  = i * 256 + t;
            const int r  = f >> 4;              // n-local row
            const int c4 = (f & 15) * 4;        // k-local (4 elems)
            const float4 w4 = *(const float4*)(Wm + (size_t)(n0 + r) * C_DIM + k0 + c4);
            u16x4 h, l;
            h.x = bf16_rne(w4.x); l.x = bf16_rne(w4.x - bf16_tof(h.x));
            h.y = bf16_rne(w4.y); l.y = bf16_rne(w4.y - bf16_tof(h.y));
            h.z = bf16_rne(w4.z); l.z = bf16_rne(w4.z - bf16_tof(h.z));
            h.w = bf16_rne(w4.w); l.w = bf16_rne(w4.w - bf16_tof(h.w));
            const int chunk = c4 >> 3;
            const int sub   = (c4 & 7) * 2;     // 0 or 8 bytes inside chunk
            const int boff  = r * 128 + ((chunk ^ (r & 7)) * 16) + sub;
            *(u16x4*)((char*)Bh + boff) = h;
            *(u16x4*)((char*)Bl + boff) = l;
        }
        __syncthreads();   // drains vmcnt (gload_lds) + lgkmcnt (ds_write)

        // ---- compute: 2 k-steps of 32, 4x4 frags, 3 MFMA passes each ----
#pragma unroll
        for (int ks = 0; ks < 2; ++ks) {
            bf16x8 afh[4], afl[4], bfh[4], bfl[4];
#pragma unroll
            for (int mt = 0; mt < 4; ++mt) {
                const int row = wm + mt * 16 + (lane & 15);
                const int ch  = (ks * 4 + (lane >> 4)) ^ (row & 7);
                const int off = row * 128 + ch * 16;
                afh[mt] = *(const bf16x8*)((const char*)Ah + off);
                afl[mt] = *(const bf16x8*)((const char*)Al + off);
            }
#pragma unroll
            for (int nt = 0; nt < 4; ++nt) {
                const int row = wn + nt * 16 + (lane & 15);
                const int ch  = (ks * 4 + (lane >> 4)) ^ (row & 7);
                const int off = row * 128 + ch * 16;
                bfh[nt] = *(const bf16x8*)((const char*)Bh + off);
                bfl[nt] = *(const bf16x8*)((const char*)Bl + off);
            }
#pragma unroll
            for (int mt = 0; mt < 4; ++mt)
#pragma unroll
                for (int nt = 0; nt < 4; ++nt) {
                    acc[mt][nt] = __builtin_amdgcn_mfma_f32_16x16x32_bf16(afh[mt], bfh[nt], acc[mt][nt], 0, 0, 0);
                    acc[mt][nt] = __builtin_amdgcn_mfma_f32_16x16x32_bf16(afh[mt], bfl[nt], acc[mt][nt], 0, 0, 0);
                    acc[mt][nt] = __builtin_amdgcn_mfma_f32_16x16x32_bf16(afl[mt], bfh[nt], acc[mt][nt], 0, 0, 0);
                }
        }
        __syncthreads();
    }

    // ---- epilogue: C/D layout col=lane&15, row=4*(lane>>4)+reg ----
    const int col = lane & 15;
    const int rg  = (lane >> 4) * 4;
#pragma unroll
    for (int nt = 0; nt < 4; ++nt) {
        const int n = n0 + wn + nt * 16 + col;
        const float bias = bm[n];
#pragma unroll
        for (int mt = 0; mt < 4; ++mt) {
            const int m = m0 + wm + mt * 16 + rg;
#pragma unroll
            for (int r = 0; r < 4; ++r)
                Out[(size_t)(m + r) * C_DIM + n] = acc[mt][nt][r] + bias;
        }
    }
}

// ---------------------------------------------------------------------------
// Q projection, f32, BITWISE-identical accumulation to round-1 (ascending-c
// fmaf chain, 16-c chunks) -> offsets/indices provably unchanged.
// Tile 64x64, 256 threads, 4x4 per thread, grid 1024 blocks.
// ---------------------------------------------------------------------------
__global__ __launch_bounds__(256) void qproj_kernel(
    const float* __restrict__ x, const float* __restrict__ Wq,
    const float* __restrict__ bq, float* __restrict__ Qt)
{
    const int b   = blockIdx.z;
    const int hw0 = blockIdx.x * 64;
    const int o0  = blockIdx.y * 64;

    __shared__ float x_s[16][64];
    __shared__ float w_s[16][68];   // padded: aligned float4 + low conflicts

    const int t  = threadIdx.x;
    const int tx = t & 15;   // hw group
    const int ty = t >> 4;   // o group

    float acc[4][4];
#pragma unroll
    for (int i = 0; i < 4; ++i)
#pragma unroll
        for (int j = 0; j < 4; ++j) acc[i][j] = 0.0f;

    const float* xb = x + (size_t)b * C_DIM * HW_DIM;

    for (int c0 = 0; c0 < C_DIM; c0 += 16) {
        // x chunk: 16 c-rows x 64 hw
        {
            const int row  = t >> 4;
            const int col4 = (t & 15) * 4;
            *(float4*)&x_s[row][col4] =
                *(const float4*)(xb + (size_t)(c0 + row) * HW_DIM + hw0 + col4);
        }
        // W chunk: 64 o-rows x 16 c, transposed into LDS
        {
            const int o  = t >> 2;
            const int c4 = (t & 3) * 4;
            const float4 v = *(const float4*)(Wq + (size_t)(o0 + o) * C_DIM + c0 + c4);
            w_s[c4 + 0][o] = v.x; w_s[c4 + 1][o] = v.y;
            w_s[c4 + 2][o] = v.z; w_s[c4 + 3][o] = v.w;
        }
        __syncthreads();

#pragma unroll
        for (int c = 0; c < 16; ++c) {
            float a[4], w[4];
            *(float4*)a = *(const float4*)&x_s[c][tx * 4];
            *(float4*)w = *(const float4*)&w_s[c][ty * 4];
#pragma unroll
            for (int i = 0; i < 4; ++i)
#pragma unroll
                for (int j = 0; j < 4; ++j)
                    acc[i][j] = fmaf(a[i], w[j], acc[i][j]);
        }
        __syncthreads();
    }

    float bias[4];
#pragma unroll
    for (int j = 0; j < 4; ++j) bias[j] = bq[o0 + ty * 4 + j];

#pragma unroll
    for (int i = 0; i < 4; ++i) {
        float4 v;
        v.x = acc[i][0] + bias[0]; v.y = acc[i][1] + bias[1];
        v.z = acc[i][2] + bias[2]; v.w = acc[i][3] + bias[3];
        *(float4*)(Qt + ((size_t)b * HW_DIM + hw0 + tx * 4 + i) * C_DIM + o0 + ty * 4) = v;
    }
}

// ---------------------------------------------------------------------------
// Stage 2: fused offsets -> indices -> gather K -> softmax -> gather V -> out.
// (unchanged from round 1)
// ---------------------------------------------------------------------------
__global__ __launch_bounds__(1024) void attn_kernel(
    const float* __restrict__ Qt,   // (B, HW, C)
    const float* __restrict__ Kt,
    const float* __restrict__ Vt,
    const float* __restrict__ Woff, // (8, C)
    const float* __restrict__ boff, // (8,)
    float* __restrict__ out)        // (B, C, HW)
{
    __shared__ float trans[16][260];

    const int t    = threadIdx.x;
    const int wave = t >> 6;
    const int lane = t & 63;

    const int pix0 = blockIdx.x * 16;
    const int b    = pix0 / HW_DIM;
    const int hw   = (pix0 % HW_DIM) + wave;
    const int h    = hw >> 6;
    const int w    = hw & 63;

    const float* qrow = Qt + ((size_t)b * HW_DIM + hw) * C_DIM;
    float q[4];
    *(float4*)q = *(const float4*)(qrow + lane * 4);

    float part[8];
#pragma unroll
    for (int j = 0; j < 8; ++j) {
        float4 wv = *(const float4*)(Woff + j * C_DIM + lane * 4);
        part[j] = fmaf(q[3], wv.w, fmaf(q[2], wv.z, fmaf(q[1], wv.y, q[0] * wv.x)));
    }
#pragma unroll
    for (int off = 1; off < 64; off <<= 1) {
#pragma unroll
        for (int j = 0; j < 8; ++j) part[j] += __shfl_xor(part[j], off);
    }

    int idx[NREF];
#pragma unroll
    for (int n = 0; n < NREF; ++n) {
        const float ox = part[2 * n]     + boff[2 * n];
        const float oy = part[2 * n + 1] + boff[2 * n + 1];
        int rx = (int)rintf((float)w + ox);
        int ry = (int)rintf((float)h + oy);
        rx = min(max(rx, 0), W_DIM - 1);
        ry = min(max(ry, 0), H_DIM - 1);
        idx[n] = ry * W_DIM + rx;
    }

    float logit[NREF];
#pragma unroll
    for (int n = 0; n < NREF; ++n) {
        const float* krow = Kt + ((size_t)b * HW_DIM + idx[n]) * C_DIM;
        float4 kv = *(const float4*)(krow + lane * 4);
        float lp = fmaf(q[3], kv.w, fmaf(q[2], kv.z, fmaf(q[1], kv.y, q[0] * kv.x)));
#pragma unroll
        for (int off = 1; off < 64; off <<= 1) lp += __shfl_xor(lp, off);
        logit[n] = lp;
    }

    float mx = fmaxf(fmaxf(logit[0], logit[1]), fmaxf(logit[2], logit[3]));
    float e[NREF], s = 0.0f;
#pragma unroll
    for (int n = 0; n < NREF; ++n) { e[n] = expf(logit[n] - mx); s += e[n]; }
    float wgt[NREF];
#pragma unroll
    for (int n = 0; n < NREF; ++n) wgt[n] = e[n] / s;

    float o4[4] = {0.f, 0.f, 0.f, 0.f};
#pragma unroll
    for (int n = 0; n < NREF; ++n) {
        const float* vrow = Vt + ((size_t)b * HW_DIM + idx[n]) * C_DIM;
        float4 vv = *(const float4*)(vrow + lane * 4);
        o4[0] = fmaf(wgt[n], vv.x, o4[0]);
        o4[1] = fmaf(wgt[n], vv.y, o4[1]);
        o4[2] = fmaf(wgt[n], vv.z, o4[2]);
        o4[3] = fmaf(wgt[n], vv.w, o4[3]);
    }

    *(float4*)&trans[wave][lane * 4] = *(float4*)o4;
    __syncthreads();

    float* ob = out + (size_t)b * C_DIM * HW_DIM + (pix0 % HW_DIM);
    const int px = t & 15;
#pragma unroll
    for (int cc = 0; cc < C_DIM; cc += 64) {
        const int c = cc + (t >> 4);
        ob[(size_t)c * HW_DIM + px] = trans[px][c];
    }
}

// ---------------------------------------------------------------------------
extern "C" void kernel_launch(void* const* d_in, const int* in_sizes, int n_in,
                              void* d_out, int out_size, void* d_ws, size_t ws_size,
                              hipStream_t stream) {
    const float* x    = (const float*)d_in[0];
    const float* Wq   = (const float*)d_in[1];
    const float* bq   = (const float*)d_in[2];
    const float* Wk   = (const float*)d_in[3];
    const float* bk   = (const float*)d_in[4];
    const float* Wv   = (const float*)d_in[5];
    const float* bv   = (const float*)d_in[6];
    const float* Woff = (const float*)d_in[7];
    const float* boff = (const float*)d_in[8];
    float* out = (float*)d_out;

    // Workspace layout (total 50,331,648 B == round-1 proven footprint):
    //   [0,16M)   Kt f32 (B*HW, C)
    //   [16M,32M) Vt f32
    //   [32M,48M) region R: xh|xl bf16 planes during prep+kv,
    //             then Qt f32 (qproj runs AFTER kv consumed xh/xl).
    char* ws = (char*)d_ws;
    float* Kt = (float*)ws;
    float* Vt = (float*)(ws + (size_t)16 * 1024 * 1024);
    float* Qt = (float*)(ws + (size_t)32 * 1024 * 1024);
    u16*   xh = (u16*)  (ws + (size_t)32 * 1024 * 1024);
    u16*   xl = (u16*)  (ws + (size_t)32 * 1024 * 1024 + 8388608);

    // 1) transpose + bf16-split x
    xsplit_kernel<<<dim3(HW_DIM / 64, C_DIM / 64, B_DIM), dim3(256), 0, stream>>>(x, xh, xl);
    // 2) K,V via split-bf16 MFMA (consumes xh/xl)
    kv_mfma<<<dim3((B_DIM * HW_DIM) / 128, C_DIM / 128, 2), dim3(256), 0, stream>>>(
        xh, xl, Wk, bk, Wv, bv, Kt, Vt);
    // 3) Q f32, bitwise round-1 accumulation (overwrites xh/xl region with Qt)
    qproj_kernel<<<dim3(HW_DIM / 64, C_DIM / 64, B_DIM), dim3(256), 0, stream>>>(x, Wq, bq, Qt);
    // 4) fused deformable attention
    attn_kernel<<<dim3((B_DIM * HW_DIM) / 16), dim3(1024), 0, stream>>>(
        Qt, Kt, Vt, Woff, boff, out);
}